// Round 6
// baseline (3648.713 us; speedup 1.0000x reference)
//
#include <hip/hip_runtime.h>
#include <stdint.h>

// ---------------------------------------------------------------------------
// BasicLSTM on MI355X — persistent pipelined 2-layer LSTM, round 11.
//
// Structure: 256 WGs x 256 threads, 1 block/CU (launch_bounds 256,1).
// 8 batch groups x 16 rows; per group 32 WGs (2 layers x 16 col-slices).
// Weights live in registers (MFMA B-frags) for all 513 epochs.
//
// ROUND-11 (on top of verified round-10, 2656 us): cut serial system-scope
// round trips per epoch.
//  * h0 buffer 3 slots deep (ws_size-guarded): anti condition weakens from
//    L1>=s to L1>=s-1, which is true at flow-gate time -> FUSED into the
//    flow poll (lanes 16..31). Removes L0's late anti round trip (~700cy).
//    Fallback (ws too small): exact round-10 2-slot + late anti.
//  * 2-deep ping-pong poll (asm global_load sc0 sc1 + counted vmcnt(1)):
//    halves the detect quantum (~700 -> ~390cy). Rule-18 mitigations:
//    early-clobber outs, "+v" dep on each waitcnt, sched_barrier(0),
//    vmcnt(0) drain at exit. (Rounds 6/7's asm bug was output/address
//    overlap on a loop-carried address; "=&v" prevents it.)
//  * Packed tags: 16 tags = one 64B sector (one coalesced poll load vs 16
//    scattered 128B-spaced sectors; ~16x less poll traffic at the MALL).
//    Producers store 4B into a shared line — distinct dwords, safe.
//  * L0 h-staging reg-split (T14): issue h loads -> 8 x-KT MFMAs as cover
//    -> LDS write. Publish moved to tid 255 so the tag-store ack never
//    sits on the polling wave's vmcnt.
// Protocol semantics unchanged: relaxed system atomics, monotone tags,
// unconditional publish, __syncthreads drains vmcnt before publish.
// ---------------------------------------------------------------------------

using s16x8 = __attribute__((ext_vector_type(8))) short;   // 8 bf16 = 4 VGPRs
using f32x4 = __attribute__((ext_vector_type(4))) float;
typedef unsigned long long ull;

#define WSB1_OFF 1572864     // L0 frags: 16*8*24*512 = 1572864 ushorts
#define HB0_OFF  3670016     // h0 slots base (ushort elems)
#define SLOT_W   65536       // words per h slot (128 rows x 512)

__device__ __forceinline__ float bf2f(unsigned short u) {
    unsigned v = ((unsigned)u) << 16;
    return __builtin_bit_cast(float, v);
}
__device__ __forceinline__ unsigned short f2bf(float f) {
    unsigned x = __builtin_bit_cast(unsigned, f);
    x += 0x7FFFu + ((x >> 16) & 1u);          // RNE (finite values only)
    return (unsigned short)(x >> 16);
}
__device__ __forceinline__ float sigm(float x) { return 1.f / (1.f + __expf(-x)); }
__device__ __forceinline__ float tanhc(float x) {
    x = fminf(15.f, fmaxf(-15.f, x));
    float e = __expf(-2.f * x);
    return (1.f - e) / (1.f + e);
}

// 2-deep ping-pong poll: wait until *tp >= thr (system-scope, MALL-served).
// Detect quantum ~ (latency+sleep)/2 instead of latency.
__device__ __forceinline__ void poll_ge2(const unsigned* tp, unsigned thr) {
    unsigned a, b;
    asm volatile("global_load_dword %0, %2, off sc0 sc1\n\t"
                 "global_load_dword %1, %2, off sc0 sc1"
                 : "=&v"(a), "=&v"(b) : "v"(tp) : "memory");
    for (;;) {
        asm volatile("s_waitcnt vmcnt(1)" : "+v"(a) : : "memory");
        __builtin_amdgcn_sched_barrier(0);
        if (a >= thr) break;
        asm volatile("global_load_dword %0, %1, off sc0 sc1"
                     : "=&v"(a) : "v"(tp) : "memory");
        asm volatile("s_waitcnt vmcnt(1)" : "+v"(b) : : "memory");
        __builtin_amdgcn_sched_barrier(0);
        if (b >= thr) break;
        asm volatile("global_load_dword %0, %1, off sc0 sc1"
                     : "=&v"(b) : "v"(tp) : "memory");
        __builtin_amdgcn_s_sleep(1);
    }
    asm volatile("s_waitcnt vmcnt(0)" ::: "memory");   // drain dangling load
    __builtin_amdgcn_sched_barrier(0);
}

// ---------------------------------------------------------------------------
// Prep: weights fp32 -> bf16 MFMA B-frags in packed-gate layout; zero the
// h slots that epoch-0/1 consumers read as "h(-1)"; zero packed tags.
// ---------------------------------------------------------------------------
__device__ __forceinline__ void store_frag(unsigned short* dst, int n, int kc, int KT,
                                           const float* src) {
    s16x8 v;
#pragma unroll
    for (int e = 0; e < 8; ++e) v[e] = (short)f2bf(src[e]);
    int gate = n >> 9, hid = n & 511;
    int rt = hid >> 5;
    int w  = (hid >> 3) & 3;
    int t  = gate >> 1;
    int lo = (gate & 1) * 8 + (hid & 7);
    int tileIdx = w * 2 + t;
    int kt = kc >> 2, q = kc & 3;
    int lane = q * 16 + lo;
    size_t off = ((((size_t)rt * 8 + tileIdx) * KT + kt) * 64 + lane) * 8;
    *(s16x8*)(dst + off) = v;
}

__global__ void k_prep(const float* __restrict__ wih0, const float* __restrict__ whh0,
                       const float* __restrict__ wih1, const float* __restrict__ whh1,
                       unsigned short* __restrict__ wsB0, unsigned short* __restrict__ wsB1,
                       unsigned short* __restrict__ hb0, unsigned short* __restrict__ hb1,
                       unsigned* __restrict__ tags, int d3) {
    int idx = blockIdx.x * 256 + threadIdx.x;
    if (idx < 196608) {                       // L0: 2048 rows x 96 k-chunks
        int n = idx / 96, kc = idx - n * 96;
        int k = kc * 8;
        const float* src = (k < 256) ? (wih0 + (size_t)n * 256 + k)
                                     : (whh0 + (size_t)n * 512 + (k - 256));
        store_frag(wsB0, n, kc, 24, src);
    } else if (idx < 458752) {                // L1: 2048 rows x 128 k-chunks
        int j = idx - 196608;
        int n = j >> 7, kc = j & 127;
        int k = kc * 8;
        const float* src = (k < 512) ? (wih1 + (size_t)n * 512 + k)
                                     : (whh1 + (size_t)n * 512 + (k - 512));
        store_frag(wsB1, n, kc, 32, src);
    } else {
        int z = idx - 458752;
        if (z < 8192) {                       // zero h0(-1): slot 2 (D3) / 1 (D2)
            ull* p = (ull*)(hb0 + (d3 ? 2 * SLOT_W : SLOT_W) + (size_t)z * 8);
            p[0] = 0ull; p[1] = 0ull;
        } else if (z < 16384) {               // zero hb1 slot 0 (h1(-1))
            ull* p = (ull*)(hb1 + (size_t)(z - 8192) * 8);
            p[0] = 0ull; p[1] = 0ull;
        } else if (z < 16640) {               // zero 256 packed tag words
            tags[z - 16384] = 0u;
        }
    }
}

// ---------------------------------------------------------------------------
// Persistent LSTM kernel
// ---------------------------------------------------------------------------
template <int LAYER, int KT, bool D3>
__device__ __forceinline__ void run_layer(const float* __restrict__ x,
                                          const unsigned short* __restrict__ wsB,
                                          unsigned short* hsrc0,   // L0: hb0 ; L1: hb0 (y0)
                                          unsigned short* hself,   // write target (hb0/hb1)
                                          unsigned* gt,            // packed 32 group tags
                                          unsigned* mytag,
                                          float bv0, float bv1,
                                          int g, int rt, int w, int lane, int tid,
                                          char* At) {
    constexpr int PITCH = (LAYER == 0) ? 1600 : 2112;   // bytes/row, ==64 mod 128
    constexpr int KTX   = 8;                            // L0 x-half KT count
    constexpr int KTY   = 16;                           // L1 y0-half KT count
    const int lm = lane & 15, lq = lane >> 4;

    // --- weight fragments into registers/AGPRs (live across all epochs) ---
    s16x8 bfr0[KT], bfr1[KT];
    {
        const unsigned short* base = wsB + (((size_t)rt * 8 + 2 * w) * KT) * 512;
#pragma unroll
        for (int kt = 0; kt < KT; ++kt) {
            bfr0[kt] = *(const s16x8*)(base + ((size_t)kt * 64 + lane) * 8);
            bfr1[kt] = *(const s16x8*)(base + (((size_t)KT + kt) * 64 + lane) * 8);
        }
    }

    float cst[4] = {0.f, 0.f, 0.f, 0.f};      // cell state: (b=lq*4+r, j=w*8+(lm&7))

    // --- x prefetch state (L0 only): x(0) preloaded before the loop ---
    f32x4 xa[2], xb[2];
    int xrow[2], xch[2];
    if (LAYER == 0) {
#pragma unroll
        for (int i = 0; i < 2; ++i) {
            int task = tid + i * 256;         // 16 rows x 32 chunks (8 fp32 each)
            xrow[i] = task >> 5; xch[i] = task & 31;
            const float* src = x + ((size_t)(g * 16 + xrow[i]) * 512) * 256 + xch[i] * 8;
            xa[i] = *(const f32x4*)(src);
            xb[i] = *(const f32x4*)(src + 4);
        }
    }

    int sw3 = 0, sr3 = 2;                     // D3 rolling slots: s%3, (s+2)%3

#pragma unroll 1
    for (int s = 0; s <= 512; ++s) {
        const bool active = LAYER ? (s >= 1) : (s < 512);
        const int rH = D3 ? sr3 : ((s + 1) & 1);   // h0/y0 read slot
        const int wH = D3 ? sw3 : (s & 1);         // h0 write slot (L0)
        const int pr2 = (s + 1) & 1;               // h1 read slot (L1)
        const int pw2 = s & 1;                     // h1 write slot (L1)

        if (active) {
            f32x4 acc0 = {0.f, 0.f, 0.f, 0.f}, acc1 = {0.f, 0.f, 0.f, 0.f};
            const char* ap = At + lm * PITCH + lq * 16;

            if (LAYER == 0) {
                // ---- pre-gate: stage x(s), prefetch x(s+1) ----
#pragma unroll
                for (int i = 0; i < 2; ++i) {
                    s16x8 v;
#pragma unroll
                    for (int e = 0; e < 4; ++e) { v[e] = (short)f2bf(xa[i][e]); v[4 + e] = (short)f2bf(xb[i][e]); }
                    *(s16x8*)(At + xrow[i] * PITCH + xch[i] * 16) = v;
                }
                if (s + 1 < 512) {
#pragma unroll
                    for (int i = 0; i < 2; ++i) {
                        const float* src = x + ((size_t)(g * 16 + xrow[i]) * 512 + (s + 1)) * 256 + xch[i] * 8;
                        xa[i] = *(const f32x4*)(src);
                        xb[i] = *(const f32x4*)(src + 4);
                    }
                }
                // no barrier here: (B) below orders x-stage writes vs reads

                // ---- gate: flow (L0>=s); D3 additionally fuses anti (L1>=s-1) ----
                if (D3) {
                    if (tid < 32) {
                        unsigned thr = (tid < 16) ? (unsigned)s
                                                  : (unsigned)(s > 0 ? s - 1 : 0);
                        poll_ge2(gt + tid, thr);
                    }
                } else {
                    if (tid < 16) poll_ge2(gt + tid, (unsigned)s);
                }
                __syncthreads();              // (B)

                // ---- reg-stage h0(s-1); x-half MFMAs cover the load latency ----
                ull hva[4], hvb[4];
                int hrw[4], hc8[4];
#pragma unroll
                for (int i = 0; i < 4; ++i) {
                    int task = tid + i * 256;
                    hrw[i] = task >> 6; hc8[i] = task & 63;
                    const ull* sp = (const ull*)(hsrc0 + (size_t)(rH * 128 + g * 16 + hrw[i]) * 512 + hc8[i] * 8);
                    hva[i] = __hip_atomic_load(sp,     __ATOMIC_RELAXED, __HIP_MEMORY_SCOPE_SYSTEM);
                    hvb[i] = __hip_atomic_load(sp + 1, __ATOMIC_RELAXED, __HIP_MEMORY_SCOPE_SYSTEM);
                }
#pragma unroll
                for (int kt = 0; kt < KTX; ++kt) {    // x-half MFMAs
                    s16x8 a = *(const s16x8*)(ap + kt * 64);
                    acc0 = __builtin_amdgcn_mfma_f32_16x16x32_bf16(a, bfr0[kt], acc0, 0, 0, 0);
                    acc1 = __builtin_amdgcn_mfma_f32_16x16x32_bf16(a, bfr1[kt], acc1, 0, 0, 0);
                }
#pragma unroll
                for (int i = 0; i < 4; ++i) {
                    ull* d = (ull*)(At + hrw[i] * PITCH + 512 + hc8[i] * 16);
                    d[0] = hva[i]; d[1] = hvb[i];
                }
                __syncthreads();              // (C) h staged

                // ---- h-half MFMAs (kt 8..23) ----
#pragma unroll
                for (int kt = KTX; kt < KT; ++kt) {
                    s16x8 a = *(const s16x8*)(ap + kt * 64);
                    acc0 = __builtin_amdgcn_mfma_f32_16x16x32_bf16(a, bfr0[kt], acc0, 0, 0, 0);
                    acc1 = __builtin_amdgcn_mfma_f32_16x16x32_bf16(a, bfr1[kt], acc1, 0, 0, 0);
                }
            } else {
                // ---- own-gate: 16 L1 tags >= s ----
                if (tid < 16) poll_ge2(gt + 16 + tid, (unsigned)s);
                __syncthreads();              // (B1)

                // ---- stage h1(s-1) -> At bytes 1024+ ----
#pragma unroll
                for (int i = 0; i < 4; ++i) {
                    int task = tid + i * 256;
                    int row = task >> 6, c8 = task & 63;
                    const ull* sp = (const ull*)(hself + (size_t)(pr2 * 128 + g * 16 + row) * 512 + c8 * 8);
                    ull v0 = __hip_atomic_load(sp,     __ATOMIC_RELAXED, __HIP_MEMORY_SCOPE_SYSTEM);
                    ull v1 = __hip_atomic_load(sp + 1, __ATOMIC_RELAXED, __HIP_MEMORY_SCOPE_SYSTEM);
                    ull* d = (ull*)(At + row * PITCH + 1024 + c8 * 16);
                    d[0] = v0; d[1] = v1;
                }
                __syncthreads();              // (C1) h1 staged

                // ---- h1-half MFMAs (kt 16..31) — overlap the wait for L0 ----
#pragma unroll
                for (int kt = KTY; kt < KT; ++kt) {
                    s16x8 a = *(const s16x8*)(ap + kt * 64);
                    acc0 = __builtin_amdgcn_mfma_f32_16x16x32_bf16(a, bfr0[kt], acc0, 0, 0, 0);
                    acc1 = __builtin_amdgcn_mfma_f32_16x16x32_bf16(a, bfr1[kt], acc1, 0, 0, 0);
                }

                // ---- cross-gate: 16 L0 tags >= s ----
                if (tid < 16) poll_ge2(gt + tid, (unsigned)s);
                __syncthreads();              // (B2)

                // ---- stage y0(s-1) -> At bytes 0..1023 ----
#pragma unroll
                for (int i = 0; i < 4; ++i) {
                    int task = tid + i * 256;
                    int row = task >> 6, c8 = task & 63;
                    const ull* sp = (const ull*)(hsrc0 + (size_t)(rH * 128 + g * 16 + row) * 512 + c8 * 8);
                    ull v0 = __hip_atomic_load(sp,     __ATOMIC_RELAXED, __HIP_MEMORY_SCOPE_SYSTEM);
                    ull v1 = __hip_atomic_load(sp + 1, __ATOMIC_RELAXED, __HIP_MEMORY_SCOPE_SYSTEM);
                    ull* d = (ull*)(At + row * PITCH + c8 * 16);
                    d[0] = v0; d[1] = v1;
                }
                __syncthreads();              // (C2) y0 staged

                // ---- y0-half MFMAs (kt 0..15) ----
#pragma unroll
                for (int kt = 0; kt < KTY; ++kt) {
                    s16x8 a = *(const s16x8*)(ap + kt * 64);
                    acc0 = __builtin_amdgcn_mfma_f32_16x16x32_bf16(a, bfr0[kt], acc0, 0, 0, 0);
                    acc1 = __builtin_amdgcn_mfma_f32_16x16x32_bf16(a, bfr1[kt], acc1, 0, 0, 0);
                }
            }

            // ---- nonlinearity via shfl_xor(8,16); no LDS round trip ----
            const bool hi = (lm & 8) != 0;
            float hv[4];
#pragma unroll
            for (int r = 0; r < 4; ++r) {
                float a0 = acc0[r] + bv0;
                float a1 = acc1[r] + bv1;
                float a0x = __shfl_xor(a0, 8, 16);
                float a1x = __shfl_xor(a1, 8, 16);
                float iv = hi ? a0x : a0;
                float fv = hi ? a0  : a0x;
                float gv = hi ? a1x : a1;
                float ov = hi ? a1  : a1x;
                float cn = sigm(fv) * cst[r] + sigm(iv) * tanhc(gv);
                cst[r] = cn;
                hv[r] = sigm(ov) * tanhc(cn);
            }

            // ---- D2 fallback only: late anti-gate (L1 readers done) ----
            if (LAYER == 0 && !D3) {
                if (tid < 16) poll_ge2(gt + 16 + tid, (unsigned)s);
                __syncthreads();              // (E)
            }

            // ---- 8x4 register transpose -> packed 8-B h stores ----
            ull packed = 0;
#pragma unroll
            for (int r = 0; r < 4; ++r)
                packed |= ((ull)f2bf(hv[r])) << (16 * r);
            ull outp = 0;
            const int rp = (lm >> 1) & 3;
#pragma unroll
            for (int e = 0; e < 4; ++e) {
                ull got = __shfl(packed, (lm & 1) * 4 + e, 16);
                ull val = (got >> (16 * rp)) & 0xFFFFull;
                outp |= val << (16 * e);
            }
            if (lm < 8) {
                int brow = lq * 4 + (lm >> 1);
                int slot = (LAYER == 0) ? wH : pw2;
                size_t off = (size_t)(slot * 128 + g * 16 + brow) * 512
                           + rt * 32 + w * 8 + (lm & 1) * 4;
                __hip_atomic_store((ull*)(hself + off), outp,
                                   __ATOMIC_RELAXED, __HIP_MEMORY_SCOPE_SYSTEM);
            }
        }

        // ---- publish: syncthreads drains vmcnt(0) per wave, then tag.
        //      tid 255 (wave 3): keeps the tag-store ack off the polling wave.
        __syncthreads();                      // (D)
        if (tid == 255)
            __hip_atomic_store(mytag, (unsigned)(s + 1),
                               __ATOMIC_RELAXED, __HIP_MEMORY_SCOPE_SYSTEM);

        if (D3) {
            sw3 = (sw3 == 2) ? 0 : sw3 + 1;
            sr3 = (sr3 == 2) ? 0 : sr3 + 1;
        }
    }
}

__launch_bounds__(256, 1)
__global__ void k_lstm(const float* __restrict__ x,
                       const float* __restrict__ b0,
                       const float* __restrict__ b1,
                       const unsigned short* __restrict__ wsB0,
                       const unsigned short* __restrict__ wsB1,
                       unsigned short* hb0, unsigned short* hb1,
                       unsigned* tags, int d3) {
    __shared__ __align__(16) char Atile[16 * 2112];      // A tile, max pitch (L1)

    const int tid = threadIdx.x;
    const int g = blockIdx.x & 7, sub = blockIdx.x >> 3;
    const int layer = sub >> 4, rt = sub & 15;
    const int w = tid >> 6, lane = tid & 63;
    const int lm = lane & 15;

    unsigned* gt = tags + (size_t)g * 32;                // packed: 32 tags = 128 B
    unsigned* mytag = gt + layer * 16 + rt;

    const float* bias = layer ? b1 : b0;
    const int jsub = rt * 32 + w * 8 + (lm & 7);
    const int G0 = (lm & 8) ? 1 : 0;                     // acc0: i | f
    const float bv0 = bias[G0 * 512 + jsub];
    const float bv1 = bias[(G0 + 2) * 512 + jsub];       // acc1: g | o

    if (layer == 0) {
        if (d3) run_layer<0, 24, true >(x, wsB0, hb0, hb0, gt, mytag, bv0, bv1,
                                        g, rt, w, lane, tid, Atile);
        else    run_layer<0, 24, false>(x, wsB0, hb0, hb0, gt, mytag, bv0, bv1,
                                        g, rt, w, lane, tid, Atile);
    } else {
        if (d3) run_layer<1, 32, true >(x, wsB1, hb0, hb1, gt, mytag, bv0, bv1,
                                        g, rt, w, lane, tid, Atile);
        else    run_layer<1, 32, false>(x, wsB1, hb0, hb1, gt, mytag, bv0, bv1,
                                        g, rt, w, lane, tid, Atile);
    }
}

// ---------------------------------------------------------------------------
// FC epilogue: out[i] = dot(hn[i], fc_w) + fc_b, hn = [h0(511); h1(511)]
// hb0fin points at h0's final slot (epoch 511: slot 511%3=2 (D3) / 1 (D2));
// h1(511) was written at epoch 512 -> slot 0 (= hb1 base).
// ---------------------------------------------------------------------------
__global__ void k_fc(const unsigned short* __restrict__ hb0fin,
                     const unsigned short* __restrict__ hb1,
                     const float* __restrict__ fcw, const float* __restrict__ fcb,
                     float* __restrict__ out) {
    int i = blockIdx.x, lane = threadIdx.x;
    const unsigned short* hrow = (i < 128) ? (hb0fin + (size_t)i * 512)
                                           : (hb1 + (size_t)(i - 128) * 512);
    float ssum = 0.f;
    int j0 = lane * 8;
#pragma unroll
    for (int e = 0; e < 8; ++e) ssum += bf2f(hrow[j0 + e]) * fcw[j0 + e];
#pragma unroll
    for (int off2 = 32; off2 > 0; off2 >>= 1) ssum += __shfl_down(ssum, off2);
    if (lane == 0) out[i] = ssum + fcb[0];
}

// ---------------------------------------------------------------------------
extern "C" void kernel_launch(void* const* d_in, const int* in_sizes, int n_in,
                              void* d_out, int out_size, void* d_ws, size_t ws_size,
                              hipStream_t stream) {
    const float* x    = (const float*)d_in[0];
    const float* wih0 = (const float*)d_in[1];
    const float* whh0 = (const float*)d_in[2];
    const float* b0   = (const float*)d_in[3];
    const float* wih1 = (const float*)d_in[4];
    const float* whh1 = (const float*)d_in[5];
    const float* b1   = (const float*)d_in[6];
    const float* fcw  = (const float*)d_in[7];
    const float* fcb  = (const float*)d_in[8];

    // D3 layout: hb0 3 slots (ends byte 7733248), hb1 2 slots (ends 7995392),
    // packed tags 1 KB (ends 7996416). D2 fallback: round-10 offsets.
    const int d3 = (ws_size >= (size_t)7996416) ? 1 : 0;

    unsigned short* wsB0 = (unsigned short*)d_ws;
    unsigned short* wsB1 = wsB0 + WSB1_OFF;
    unsigned short* hb0  = wsB0 + HB0_OFF;
    unsigned short* hb1  = hb0 + (d3 ? 3 : 2) * SLOT_W;
    unsigned* tags = (unsigned*)((char*)d_ws + (d3 ? 7995392 : 7864320));
    unsigned short* hb0fin = hb0 + (d3 ? 2 : 1) * SLOT_W;
    float* out = (float*)d_out;

    k_prep<<<dim3(1857), dim3(256), 0, stream>>>(wih0, whh0, wih1, whh1,
                                                 wsB0, wsB1, hb0, hb1, tags, d3);

    k_lstm<<<dim3(256), dim3(256), 0, stream>>>(x, b0, b1, wsB0, wsB1, hb0, hb1,
                                                tags, d3);

    k_fc<<<dim3(256), dim3(64), 0, stream>>>(hb0fin, hb1, fcw, fcb, out);
}

// Round 7
// 3214.605 us; speedup vs baseline: 1.1350x; 1.1350x over previous
//
#include <hip/hip_runtime.h>
#include <stdint.h>

// ---------------------------------------------------------------------------
// BasicLSTM on MI355X — persistent pipelined 2-layer LSTM, round 12.
//
// Structure: 256 WGs x 256 threads, 1 block/CU (launch_bounds 256,1).
// 8 batch groups x 16 rows; per group 32 WGs (2 layers x 16 col-slices).
// Weights live in registers (MFMA B-frags) for all 513 epochs.
//
// ROUND-12 (bisect of round-11's compound regression, on verified round-10):
//  * REVERTED: asm ping-pong poll (its exit drained a dangling in-flight
//    load -> +1 full system round trip AFTER every detect; +4800cy/epoch).
//    Polls are the verified relaxed system-scope atomic-load loops.
//  * REVERTED: L0 reg-staged h + tid-255 publish -> round-10 exact forms.
//  * KEPT: h0 buffer 3 slots deep (ws-guarded). Anti condition weakens from
//    L1>=s to L1>=s-1 -> FUSED into L0's flow gate (lanes 16..31 poll L1
//    tags at threshold s-1). Deletes the late anti-gate's serial ~700cy
//    round trip; L0 can run ahead, so L1's cross-gate is pre-satisfied.
//  * KEPT: packed tags (32 tags = one 128-B line per group; 16-lane poll
//    coalesces to one sector read). Producers store distinct dwords.
//  * FIXED: k_fc h0-final slot = epoch 511 -> slot 511%3 = 1 (round-11
//    read slot 2 = h0(509): the absmax=0.5 bug). D2 also slot 1.
// Anti audit (D3): L0@s overwrites slot s%3, last written s-3, read at
// epoch s-2 by L0 peers (flow gate L0>=s covers: peers completed s-1) and
// by L1@s-2 (covered by fused L1>=s-1: published after completing s-2).
// Deadlock: L0@s waits L1-pub(s-1) -> waits L0-pub(s-2): strictly earlier
// epochs, no cycle. Induction from tags=0.
// ---------------------------------------------------------------------------

using s16x8 = __attribute__((ext_vector_type(8))) short;   // 8 bf16 = 4 VGPRs
using f32x4 = __attribute__((ext_vector_type(4))) float;
typedef unsigned long long ull;

#define WSB1_OFF 1572864     // L0 frags: 16*8*24*512 = 1572864 ushorts
#define HB0_OFF  3670016     // h0 slots base (ushort elems)
#define SLOT_W   65536       // words per h slot (128 rows x 512)

__device__ __forceinline__ float bf2f(unsigned short u) {
    unsigned v = ((unsigned)u) << 16;
    return __builtin_bit_cast(float, v);
}
__device__ __forceinline__ unsigned short f2bf(float f) {
    unsigned x = __builtin_bit_cast(unsigned, f);
    x += 0x7FFFu + ((x >> 16) & 1u);          // RNE (finite values only)
    return (unsigned short)(x >> 16);
}
__device__ __forceinline__ float sigm(float x) { return 1.f / (1.f + __expf(-x)); }
__device__ __forceinline__ float tanhc(float x) {
    x = fminf(15.f, fmaxf(-15.f, x));
    float e = __expf(-2.f * x);
    return (1.f - e) / (1.f + e);
}
__device__ __forceinline__ unsigned tagld(const unsigned* p) {
    return __hip_atomic_load(p, __ATOMIC_RELAXED, __HIP_MEMORY_SCOPE_SYSTEM);
}

// ---------------------------------------------------------------------------
// Prep: weights fp32 -> bf16 MFMA B-frags in packed-gate layout; zero the
// h slots that epoch-0/1 consumers read as "h(-1)"; zero packed tags.
// ---------------------------------------------------------------------------
__device__ __forceinline__ void store_frag(unsigned short* dst, int n, int kc, int KT,
                                           const float* src) {
    s16x8 v;
#pragma unroll
    for (int e = 0; e < 8; ++e) v[e] = (short)f2bf(src[e]);
    int gate = n >> 9, hid = n & 511;
    int rt = hid >> 5;
    int w  = (hid >> 3) & 3;
    int t  = gate >> 1;
    int lo = (gate & 1) * 8 + (hid & 7);
    int tileIdx = w * 2 + t;
    int kt = kc >> 2, q = kc & 3;
    int lane = q * 16 + lo;
    size_t off = ((((size_t)rt * 8 + tileIdx) * KT + kt) * 64 + lane) * 8;
    *(s16x8*)(dst + off) = v;
}

__global__ void k_prep(const float* __restrict__ wih0, const float* __restrict__ whh0,
                       const float* __restrict__ wih1, const float* __restrict__ whh1,
                       unsigned short* __restrict__ wsB0, unsigned short* __restrict__ wsB1,
                       unsigned short* __restrict__ hb0, unsigned short* __restrict__ hb1,
                       unsigned* __restrict__ tags, int d3) {
    int idx = blockIdx.x * 256 + threadIdx.x;
    if (idx < 196608) {                       // L0: 2048 rows x 96 k-chunks
        int n = idx / 96, kc = idx - n * 96;
        int k = kc * 8;
        const float* src = (k < 256) ? (wih0 + (size_t)n * 256 + k)
                                     : (whh0 + (size_t)n * 512 + (k - 256));
        store_frag(wsB0, n, kc, 24, src);
    } else if (idx < 458752) {                // L1: 2048 rows x 128 k-chunks
        int j = idx - 196608;
        int n = j >> 7, kc = j & 127;
        int k = kc * 8;
        const float* src = (k < 512) ? (wih1 + (size_t)n * 512 + k)
                                     : (whh1 + (size_t)n * 512 + (k - 512));
        store_frag(wsB1, n, kc, 32, src);
    } else {
        int z = idx - 458752;
        if (z < 8192) {                       // zero h0(-1): slot 2 (D3) / 1 (D2)
            ull* p = (ull*)(hb0 + (d3 ? 2 * SLOT_W : SLOT_W) + (size_t)z * 8);
            p[0] = 0ull; p[1] = 0ull;
        } else if (z < 16384) {               // zero hb1 slot 0 (h1(-1))
            ull* p = (ull*)(hb1 + (size_t)(z - 8192) * 8);
            p[0] = 0ull; p[1] = 0ull;
        } else if (z < 16640) {               // zero 256 packed tag words
            tags[z - 16384] = 0u;
        }
    }
}

// ---------------------------------------------------------------------------
// Persistent LSTM kernel
// ---------------------------------------------------------------------------
template <int LAYER, int KT, bool D3>
__device__ __forceinline__ void run_layer(const float* __restrict__ x,
                                          const unsigned short* __restrict__ wsB,
                                          unsigned short* hsrc0,   // L0: hb0 ; L1: hb0 (y0)
                                          unsigned short* hself,   // write target (hb0/hb1)
                                          unsigned* gt,            // packed 32 group tags
                                          unsigned* mytag,
                                          float bv0, float bv1,
                                          int g, int rt, int w, int lane, int tid,
                                          char* At) {
    constexpr int PITCH = (LAYER == 0) ? 1600 : 2112;   // bytes/row, ==64 mod 128
    constexpr int KTX   = 8;                            // L0 x-half KT count
    constexpr int KTY   = 16;                           // L1 y0-half KT count
    const int lm = lane & 15, lq = lane >> 4;

    // --- weight fragments into registers/AGPRs (live across all epochs) ---
    s16x8 bfr0[KT], bfr1[KT];
    {
        const unsigned short* base = wsB + (((size_t)rt * 8 + 2 * w) * KT) * 512;
#pragma unroll
        for (int kt = 0; kt < KT; ++kt) {
            bfr0[kt] = *(const s16x8*)(base + ((size_t)kt * 64 + lane) * 8);
            bfr1[kt] = *(const s16x8*)(base + (((size_t)KT + kt) * 64 + lane) * 8);
        }
    }

    float cst[4] = {0.f, 0.f, 0.f, 0.f};      // cell state: (b=lq*4+r, j=w*8+(lm&7))

    // --- x prefetch state (L0 only): x(0) preloaded before the loop ---
    f32x4 xa[2], xb[2];
    int xrow[2], xch[2];
    if (LAYER == 0) {
#pragma unroll
        for (int i = 0; i < 2; ++i) {
            int task = tid + i * 256;         // 16 rows x 32 chunks (8 fp32 each)
            xrow[i] = task >> 5; xch[i] = task & 31;
            const float* src = x + ((size_t)(g * 16 + xrow[i]) * 512) * 256 + xch[i] * 8;
            xa[i] = *(const f32x4*)(src);
            xb[i] = *(const f32x4*)(src + 4);
        }
    }

    int sw3 = 0, sr3 = 2;                     // D3 rolling h0 slots: s%3, (s+2)%3

#pragma unroll 1
    for (int s = 0; s <= 512; ++s) {
        const bool active = LAYER ? (s >= 1) : (s < 512);
        const int rH = D3 ? sr3 : ((s + 1) & 1);   // h0/y0 read slot
        const int wH = D3 ? sw3 : (s & 1);         // h0 write slot (L0)
        const int pr2 = (s + 1) & 1;               // h1 read slot (L1)
        const int pw2 = s & 1;                     // h1 write slot (L1)

        if (active) {
            f32x4 acc0 = {0.f, 0.f, 0.f, 0.f}, acc1 = {0.f, 0.f, 0.f, 0.f};
            const char* ap = At + lm * PITCH + lq * 16;

            if (LAYER == 0) {
                // ---- pre-gate: stage x(s), prefetch x(s+1) ----
#pragma unroll
                for (int i = 0; i < 2; ++i) {
                    s16x8 v;
#pragma unroll
                    for (int e = 0; e < 4; ++e) { v[e] = (short)f2bf(xa[i][e]); v[4 + e] = (short)f2bf(xb[i][e]); }
                    *(s16x8*)(At + xrow[i] * PITCH + xch[i] * 16) = v;
                }
                if (s + 1 < 512) {
#pragma unroll
                    for (int i = 0; i < 2; ++i) {
                        const float* src = x + ((size_t)(g * 16 + xrow[i]) * 512 + (s + 1)) * 256 + xch[i] * 8;
                        xa[i] = *(const f32x4*)(src);
                        xb[i] = *(const f32x4*)(src + 4);
                    }
                }
                __syncthreads();              // (A) x staged

                // ---- x-half MFMAs (no inter-WG dependency) ----
#pragma unroll
                for (int kt = 0; kt < KTX; ++kt) {
                    s16x8 a = *(const s16x8*)(ap + kt * 64);
                    acc0 = __builtin_amdgcn_mfma_f32_16x16x32_bf16(a, bfr0[kt], acc0, 0, 0, 0);
                    acc1 = __builtin_amdgcn_mfma_f32_16x16x32_bf16(a, bfr1[kt], acc1, 0, 0, 0);
                }

                // ---- flow-gate (+ fused anti when D3) ----
                if (D3) {
                    if (tid < 32) {           // lanes 0..15: L0>=s; 16..31: L1>=s-1
                        unsigned thr = (tid < 16) ? (unsigned)s
                                                  : (unsigned)(s > 0 ? s - 1 : 0);
                        const unsigned* tp = gt + tid;
                        while (tagld(tp) < thr) __builtin_amdgcn_s_sleep(1);
                    }
                } else {
                    if (tid < 16) {
                        const unsigned* tp = gt + tid;
                        while (tagld(tp) < (unsigned)s) __builtin_amdgcn_s_sleep(1);
                    }
                }
                __syncthreads();              // (B)

                // ---- stage h0(s-1): 16 rows x 64 chunks (16 B) ----
#pragma unroll
                for (int i = 0; i < 4; ++i) {
                    int task = tid + i * 256;
                    int row = task >> 6, c8 = task & 63;
                    const ull* sp = (const ull*)(hsrc0 + (size_t)(rH * 128 + g * 16 + row) * 512 + c8 * 8);
                    ull v0 = __hip_atomic_load(sp,     __ATOMIC_RELAXED, __HIP_MEMORY_SCOPE_SYSTEM);
                    ull v1 = __hip_atomic_load(sp + 1, __ATOMIC_RELAXED, __HIP_MEMORY_SCOPE_SYSTEM);
                    ull* d = (ull*)(At + row * PITCH + 512 + c8 * 16);
                    d[0] = v0; d[1] = v1;
                }
                __syncthreads();              // (C) h staged

                // ---- h-half MFMAs (kt 8..23) ----
#pragma unroll
                for (int kt = KTX; kt < KT; ++kt) {
                    s16x8 a = *(const s16x8*)(ap + kt * 64);
                    acc0 = __builtin_amdgcn_mfma_f32_16x16x32_bf16(a, bfr0[kt], acc0, 0, 0, 0);
                    acc1 = __builtin_amdgcn_mfma_f32_16x16x32_bf16(a, bfr1[kt], acc1, 0, 0, 0);
                }
            } else {
                // ---- own-gate: 16 L1 tags >= s ----
                if (tid < 16) {
                    const unsigned* tp = gt + 16 + tid;
                    while (tagld(tp) < (unsigned)s) __builtin_amdgcn_s_sleep(1);
                }
                __syncthreads();              // (B1)

                // ---- stage h1(s-1) -> At bytes 1024+ ----
#pragma unroll
                for (int i = 0; i < 4; ++i) {
                    int task = tid + i * 256;
                    int row = task >> 6, c8 = task & 63;
                    const ull* sp = (const ull*)(hself + (size_t)(pr2 * 128 + g * 16 + row) * 512 + c8 * 8);
                    ull v0 = __hip_atomic_load(sp,     __ATOMIC_RELAXED, __HIP_MEMORY_SCOPE_SYSTEM);
                    ull v1 = __hip_atomic_load(sp + 1, __ATOMIC_RELAXED, __HIP_MEMORY_SCOPE_SYSTEM);
                    ull* d = (ull*)(At + row * PITCH + 1024 + c8 * 16);
                    d[0] = v0; d[1] = v1;
                }
                __syncthreads();              // (C1) h1 staged

                // ---- h1-half MFMAs (kt 16..31) — overlap the wait for L0 ----
#pragma unroll
                for (int kt = KTY; kt < KT; ++kt) {
                    s16x8 a = *(const s16x8*)(ap + kt * 64);
                    acc0 = __builtin_amdgcn_mfma_f32_16x16x32_bf16(a, bfr0[kt], acc0, 0, 0, 0);
                    acc1 = __builtin_amdgcn_mfma_f32_16x16x32_bf16(a, bfr1[kt], acc1, 0, 0, 0);
                }

                // ---- cross-gate: 16 L0 tags >= s ----
                if (tid < 16) {
                    const unsigned* tp = gt + tid;
                    while (tagld(tp) < (unsigned)s) __builtin_amdgcn_s_sleep(1);
                }
                __syncthreads();              // (B2)

                // ---- stage y0(s-1) -> At bytes 0..1023 ----
#pragma unroll
                for (int i = 0; i < 4; ++i) {
                    int task = tid + i * 256;
                    int row = task >> 6, c8 = task & 63;
                    const ull* sp = (const ull*)(hsrc0 + (size_t)(rH * 128 + g * 16 + row) * 512 + c8 * 8);
                    ull v0 = __hip_atomic_load(sp,     __ATOMIC_RELAXED, __HIP_MEMORY_SCOPE_SYSTEM);
                    ull v1 = __hip_atomic_load(sp + 1, __ATOMIC_RELAXED, __HIP_MEMORY_SCOPE_SYSTEM);
                    ull* d = (ull*)(At + row * PITCH + c8 * 16);
                    d[0] = v0; d[1] = v1;
                }
                __syncthreads();              // (C2) y0 staged

                // ---- y0-half MFMAs (kt 0..15) ----
#pragma unroll
                for (int kt = 0; kt < KTY; ++kt) {
                    s16x8 a = *(const s16x8*)(ap + kt * 64);
                    acc0 = __builtin_amdgcn_mfma_f32_16x16x32_bf16(a, bfr0[kt], acc0, 0, 0, 0);
                    acc1 = __builtin_amdgcn_mfma_f32_16x16x32_bf16(a, bfr1[kt], acc1, 0, 0, 0);
                }
            }

            // ---- nonlinearity via shfl_xor(8,16); no LDS round trip ----
            const bool hi = (lm & 8) != 0;
            float hv[4];
#pragma unroll
            for (int r = 0; r < 4; ++r) {
                float a0 = acc0[r] + bv0;
                float a1 = acc1[r] + bv1;
                float a0x = __shfl_xor(a0, 8, 16);
                float a1x = __shfl_xor(a1, 8, 16);
                float iv = hi ? a0x : a0;
                float fv = hi ? a0  : a0x;
                float gv = hi ? a1x : a1;
                float ov = hi ? a1  : a1x;
                float cn = sigm(fv) * cst[r] + sigm(iv) * tanhc(gv);
                cst[r] = cn;
                hv[r] = sigm(ov) * tanhc(cn);
            }

            // ---- D2 fallback only: late anti-gate (L1 readers done) ----
            if (LAYER == 0 && !D3) {
                if (tid < 16) {
                    const unsigned* tp = gt + 16 + tid;
                    while (tagld(tp) < (unsigned)s) __builtin_amdgcn_s_sleep(1);
                }
                __syncthreads();              // (E)
            }

            // ---- 8x4 register transpose -> packed 8-B h stores ----
            ull packed = 0;
#pragma unroll
            for (int r = 0; r < 4; ++r)
                packed |= ((ull)f2bf(hv[r])) << (16 * r);
            ull outp = 0;
            const int rp = (lm >> 1) & 3;
#pragma unroll
            for (int e = 0; e < 4; ++e) {
                ull got = __shfl(packed, (lm & 1) * 4 + e, 16);
                ull val = (got >> (16 * rp)) & 0xFFFFull;
                outp |= val << (16 * e);
            }
            if (lm < 8) {
                int brow = lq * 4 + (lm >> 1);
                int slot = (LAYER == 0) ? wH : pw2;
                size_t off = (size_t)(slot * 128 + g * 16 + brow) * 512
                           + rt * 32 + w * 8 + (lm & 1) * 4;
                __hip_atomic_store((ull*)(hself + off), outp,
                                   __ATOMIC_RELAXED, __HIP_MEMORY_SCOPE_SYSTEM);
            }
        }

        // ---- publish: syncthreads drains vmcnt(0) per wave, then tag ----
        __syncthreads();                      // (D)
        if (tid == 0)
            __hip_atomic_store(mytag, (unsigned)(s + 1),
                               __ATOMIC_RELAXED, __HIP_MEMORY_SCOPE_SYSTEM);

        if (D3) {
            sw3 = (sw3 == 2) ? 0 : sw3 + 1;
            sr3 = (sr3 == 2) ? 0 : sr3 + 1;
        }
    }
}

__launch_bounds__(256, 1)
__global__ void k_lstm(const float* __restrict__ x,
                       const float* __restrict__ b0,
                       const float* __restrict__ b1,
                       const unsigned short* __restrict__ wsB0,
                       const unsigned short* __restrict__ wsB1,
                       unsigned short* hb0, unsigned short* hb1,
                       unsigned* tags, int d3) {
    __shared__ __align__(16) char Atile[16 * 2112];      // A tile, max pitch (L1)

    const int tid = threadIdx.x;
    const int g = blockIdx.x & 7, sub = blockIdx.x >> 3;
    const int layer = sub >> 4, rt = sub & 15;
    const int w = tid >> 6, lane = tid & 63;
    const int lm = lane & 15;

    unsigned* gt = tags + (size_t)g * 32;                // packed: 32 tags = 128 B
    unsigned* mytag = gt + layer * 16 + rt;

    const float* bias = layer ? b1 : b0;
    const int jsub = rt * 32 + w * 8 + (lm & 7);
    const int G0 = (lm & 8) ? 1 : 0;                     // acc0: i | f
    const float bv0 = bias[G0 * 512 + jsub];
    const float bv1 = bias[(G0 + 2) * 512 + jsub];       // acc1: g | o

    if (layer == 0) {
        if (d3) run_layer<0, 24, true >(x, wsB0, hb0, hb0, gt, mytag, bv0, bv1,
                                        g, rt, w, lane, tid, Atile);
        else    run_layer<0, 24, false>(x, wsB0, hb0, hb0, gt, mytag, bv0, bv1,
                                        g, rt, w, lane, tid, Atile);
    } else {
        if (d3) run_layer<1, 32, true >(x, wsB1, hb0, hb1, gt, mytag, bv0, bv1,
                                        g, rt, w, lane, tid, Atile);
        else    run_layer<1, 32, false>(x, wsB1, hb0, hb1, gt, mytag, bv0, bv1,
                                        g, rt, w, lane, tid, Atile);
    }
}

// ---------------------------------------------------------------------------
// FC epilogue: out[i] = dot(hn[i], fc_w) + fc_b, hn = [h0(511); h1(511)]
// h0(511): epoch 511 -> slot 511%3 = 1 (D3) / 511&1 = 1 (D2) -> hb0+SLOT_W.
// h1(511): written at epoch 512 -> slot 0 (= hb1 base).
// ---------------------------------------------------------------------------
__global__ void k_fc(const unsigned short* __restrict__ hb0fin,
                     const unsigned short* __restrict__ hb1,
                     const float* __restrict__ fcw, const float* __restrict__ fcb,
                     float* __restrict__ out) {
    int i = blockIdx.x, lane = threadIdx.x;
    const unsigned short* hrow = (i < 128) ? (hb0fin + (size_t)i * 512)
                                           : (hb1 + (size_t)(i - 128) * 512);
    float ssum = 0.f;
    int j0 = lane * 8;
#pragma unroll
    for (int e = 0; e < 8; ++e) ssum += bf2f(hrow[j0 + e]) * fcw[j0 + e];
#pragma unroll
    for (int off2 = 32; off2 > 0; off2 >>= 1) ssum += __shfl_down(ssum, off2);
    if (lane == 0) out[i] = ssum + fcb[0];
}

// ---------------------------------------------------------------------------
extern "C" void kernel_launch(void* const* d_in, const int* in_sizes, int n_in,
                              void* d_out, int out_size, void* d_ws, size_t ws_size,
                              hipStream_t stream) {
    const float* x    = (const float*)d_in[0];
    const float* wih0 = (const float*)d_in[1];
    const float* whh0 = (const float*)d_in[2];
    const float* b0   = (const float*)d_in[3];
    const float* wih1 = (const float*)d_in[4];
    const float* whh1 = (const float*)d_in[5];
    const float* b1   = (const float*)d_in[6];
    const float* fcw  = (const float*)d_in[7];
    const float* fcb  = (const float*)d_in[8];

    // D3 layout: hb0 3 slots, hb1 2 slots (ends byte 7995392), packed tags
    // 1 KB at 7995392 (ends 7996416). D2 fallback: hb0 2 slots, hb1 2 slots
    // (ends 7864320), packed tags at 7864320.
    const int d3 = (ws_size >= (size_t)7996416) ? 1 : 0;

    unsigned short* wsB0 = (unsigned short*)d_ws;
    unsigned short* wsB1 = wsB0 + WSB1_OFF;
    unsigned short* hb0  = wsB0 + HB0_OFF;
    unsigned short* hb1  = hb0 + (d3 ? 3 : 2) * SLOT_W;
    unsigned* tags = (unsigned*)((char*)d_ws + (d3 ? 7995392 : 7864320));
    unsigned short* hb0fin = hb0 + SLOT_W;               // slot 1 (both layouts)
    float* out = (float*)d_out;

    k_prep<<<dim3(1857), dim3(256), 0, stream>>>(wih0, whh0, wih1, whh1,
                                                 wsB0, wsB1, hb0, hb1, tags, d3);

    k_lstm<<<dim3(256), dim3(256), 0, stream>>>(x, b0, b1, wsB0, wsB1, hb0, hb1,
                                                tags, d3);

    k_fc<<<dim3(256), dim3(64), 0, stream>>>(hb0fin, hb1, fcw, fcb, out);
}

// Round 8
// 2642.661 us; speedup vs baseline: 1.3807x; 1.2164x over previous
//
#include <hip/hip_runtime.h>
#include <stdint.h>

// ---------------------------------------------------------------------------
// BasicLSTM on MI355X — persistent pipelined 2-layer LSTM, round 13.
//
// Structure: 256 WGs x 256 threads, 1 block/CU (launch_bounds 256,1).
// 8 batch groups x 16 rows; per group 32 WGs (2 layers x 16 col-slices).
// Weights live in registers (MFMA B-frags) for all 513 epochs.
//
// ROUND-13 (bisect round-12's +559us regression):
//  * REVERTED: packed tags. All 32 producers stored into ONE 128-B line
//    per group and all 32 consumers polled that line -> every publish
//    serialized against 31 publishes + the poll stream at the MALL sector
//    (false sharing at the coherence point; ~+2600cy/epoch). Tags are back
//    to the verified scattered layout: one tag per 128-B block.
//  * KEPT: h0 buffer 3 slots deep (D3, ws-guarded) with the anti condition
//    weakened to L1>=s-1 and FUSED into L0's flow gate (lanes 16..31 at
//    threshold s-1). Mechanism: waits on strictly less, strictly earlier
//    than round-10's late anti-gate; deletes its serial ~700cy round trip.
//  * KEPT: k_fc h0-final = slot 1 (epoch 511 -> 511%3 = 1; D2 also 1).
// Anti audit (D3): L0@s overwrites slot s%3, last read by L0 peers at
// epoch s-2 (flow gate L0>=s covers) and by L1@s-2 (fused L1>=s-1 covers).
// Deadlock: L0@s waits L1-pub(s-1) -> waits L0-pub(s-2): strictly earlier
// epochs, no cycle. Induction from tags=0.
// ---------------------------------------------------------------------------

using s16x8 = __attribute__((ext_vector_type(8))) short;   // 8 bf16 = 4 VGPRs
using f32x4 = __attribute__((ext_vector_type(4))) float;
typedef unsigned long long ull;

#define WSB1_OFF 1572864     // L0 frags: 16*8*24*512 = 1572864 ushorts
#define HB0_OFF  3670016     // h0 slots base (ushort elems)
#define SLOT_W   65536       // words per h slot (128 rows x 512)

__device__ __forceinline__ float bf2f(unsigned short u) {
    unsigned v = ((unsigned)u) << 16;
    return __builtin_bit_cast(float, v);
}
__device__ __forceinline__ unsigned short f2bf(float f) {
    unsigned x = __builtin_bit_cast(unsigned, f);
    x += 0x7FFFu + ((x >> 16) & 1u);          // RNE (finite values only)
    return (unsigned short)(x >> 16);
}
__device__ __forceinline__ float sigm(float x) { return 1.f / (1.f + __expf(-x)); }
__device__ __forceinline__ float tanhc(float x) {
    x = fminf(15.f, fmaxf(-15.f, x));
    float e = __expf(-2.f * x);
    return (1.f - e) / (1.f + e);
}
__device__ __forceinline__ unsigned tagld(const unsigned* p) {
    return __hip_atomic_load(p, __ATOMIC_RELAXED, __HIP_MEMORY_SCOPE_SYSTEM);
}

// ---------------------------------------------------------------------------
// Prep: weights fp32 -> bf16 MFMA B-frags in packed-gate layout; zero the
// h slots that epoch-0/1 consumers read as "h(-1)"; zero scattered tags.
// ---------------------------------------------------------------------------
__device__ __forceinline__ void store_frag(unsigned short* dst, int n, int kc, int KT,
                                           const float* src) {
    s16x8 v;
#pragma unroll
    for (int e = 0; e < 8; ++e) v[e] = (short)f2bf(src[e]);
    int gate = n >> 9, hid = n & 511;
    int rt = hid >> 5;
    int w  = (hid >> 3) & 3;
    int t  = gate >> 1;
    int lo = (gate & 1) * 8 + (hid & 7);
    int tileIdx = w * 2 + t;
    int kt = kc >> 2, q = kc & 3;
    int lane = q * 16 + lo;
    size_t off = ((((size_t)rt * 8 + tileIdx) * KT + kt) * 64 + lane) * 8;
    *(s16x8*)(dst + off) = v;
}

__global__ void k_prep(const float* __restrict__ wih0, const float* __restrict__ whh0,
                       const float* __restrict__ wih1, const float* __restrict__ whh1,
                       unsigned short* __restrict__ wsB0, unsigned short* __restrict__ wsB1,
                       unsigned short* __restrict__ hb0, unsigned short* __restrict__ hb1,
                       unsigned* __restrict__ tags, int d3) {
    int idx = blockIdx.x * 256 + threadIdx.x;
    if (idx < 196608) {                       // L0: 2048 rows x 96 k-chunks
        int n = idx / 96, kc = idx - n * 96;
        int k = kc * 8;
        const float* src = (k < 256) ? (wih0 + (size_t)n * 256 + k)
                                     : (whh0 + (size_t)n * 512 + (k - 256));
        store_frag(wsB0, n, kc, 24, src);
    } else if (idx < 458752) {                // L1: 2048 rows x 128 k-chunks
        int j = idx - 196608;
        int n = j >> 7, kc = j & 127;
        int k = kc * 8;
        const float* src = (k < 512) ? (wih1 + (size_t)n * 512 + k)
                                     : (whh1 + (size_t)n * 512 + (k - 512));
        store_frag(wsB1, n, kc, 32, src);
    } else {
        int z = idx - 458752;
        if (z < 8192) {                       // zero h0(-1): slot 2 (D3) / 1 (D2)
            ull* p = (ull*)(hb0 + (d3 ? 2 * SLOT_W : SLOT_W) + (size_t)z * 8);
            p[0] = 0ull; p[1] = 0ull;
        } else if (z < 16384) {               // zero hb1 slot 0 (h1(-1))
            ull* p = (ull*)(hb1 + (size_t)(z - 8192) * 8);
            p[0] = 0ull; p[1] = 0ull;
        } else if (z < 16640) {               // zero 256 tag words (128-B spaced)
            tags[(size_t)(z - 16384) * 32] = 0u;
        }
    }
}

// ---------------------------------------------------------------------------
// Persistent LSTM kernel
// ---------------------------------------------------------------------------
template <int LAYER, int KT, bool D3>
__device__ __forceinline__ void run_layer(const float* __restrict__ x,
                                          const unsigned short* __restrict__ wsB,
                                          unsigned short* hsrc0,   // L0: hb0 ; L1: hb0 (y0)
                                          unsigned short* hself,   // write target (hb0/hb1)
                                          unsigned* gt,            // group tag base (32 tags, 128-B spaced)
                                          unsigned* mytag,
                                          float bv0, float bv1,
                                          int g, int rt, int w, int lane, int tid,
                                          char* At) {
    constexpr int PITCH = (LAYER == 0) ? 1600 : 2112;   // bytes/row, ==64 mod 128
    constexpr int KTX   = 8;                            // L0 x-half KT count
    constexpr int KTY   = 16;                           // L1 y0-half KT count
    const int lm = lane & 15, lq = lane >> 4;

    // --- weight fragments into registers/AGPRs (live across all epochs) ---
    s16x8 bfr0[KT], bfr1[KT];
    {
        const unsigned short* base = wsB + (((size_t)rt * 8 + 2 * w) * KT) * 512;
#pragma unroll
        for (int kt = 0; kt < KT; ++kt) {
            bfr0[kt] = *(const s16x8*)(base + ((size_t)kt * 64 + lane) * 8);
            bfr1[kt] = *(const s16x8*)(base + (((size_t)KT + kt) * 64 + lane) * 8);
        }
    }

    float cst[4] = {0.f, 0.f, 0.f, 0.f};      // cell state: (b=lq*4+r, j=w*8+(lm&7))

    // --- x prefetch state (L0 only): x(0) preloaded before the loop ---
    f32x4 xa[2], xb[2];
    int xrow[2], xch[2];
    if (LAYER == 0) {
#pragma unroll
        for (int i = 0; i < 2; ++i) {
            int task = tid + i * 256;         // 16 rows x 32 chunks (8 fp32 each)
            xrow[i] = task >> 5; xch[i] = task & 31;
            const float* src = x + ((size_t)(g * 16 + xrow[i]) * 512) * 256 + xch[i] * 8;
            xa[i] = *(const f32x4*)(src);
            xb[i] = *(const f32x4*)(src + 4);
        }
    }

    int sw3 = 0, sr3 = 2;                     // D3 rolling h0 slots: s%3, (s+2)%3

#pragma unroll 1
    for (int s = 0; s <= 512; ++s) {
        const bool active = LAYER ? (s >= 1) : (s < 512);
        const int rH = D3 ? sr3 : ((s + 1) & 1);   // h0/y0 read slot
        const int wH = D3 ? sw3 : (s & 1);         // h0 write slot (L0)
        const int pr2 = (s + 1) & 1;               // h1 read slot (L1)
        const int pw2 = s & 1;                     // h1 write slot (L1)

        if (active) {
            f32x4 acc0 = {0.f, 0.f, 0.f, 0.f}, acc1 = {0.f, 0.f, 0.f, 0.f};
            const char* ap = At + lm * PITCH + lq * 16;

            if (LAYER == 0) {
                // ---- pre-gate: stage x(s), prefetch x(s+1) ----
#pragma unroll
                for (int i = 0; i < 2; ++i) {
                    s16x8 v;
#pragma unroll
                    for (int e = 0; e < 4; ++e) { v[e] = (short)f2bf(xa[i][e]); v[4 + e] = (short)f2bf(xb[i][e]); }
                    *(s16x8*)(At + xrow[i] * PITCH + xch[i] * 16) = v;
                }
                if (s + 1 < 512) {
#pragma unroll
                    for (int i = 0; i < 2; ++i) {
                        const float* src = x + ((size_t)(g * 16 + xrow[i]) * 512 + (s + 1)) * 256 + xch[i] * 8;
                        xa[i] = *(const f32x4*)(src);
                        xb[i] = *(const f32x4*)(src + 4);
                    }
                }
                __syncthreads();              // (A) x staged

                // ---- x-half MFMAs (no inter-WG dependency) ----
#pragma unroll
                for (int kt = 0; kt < KTX; ++kt) {
                    s16x8 a = *(const s16x8*)(ap + kt * 64);
                    acc0 = __builtin_amdgcn_mfma_f32_16x16x32_bf16(a, bfr0[kt], acc0, 0, 0, 0);
                    acc1 = __builtin_amdgcn_mfma_f32_16x16x32_bf16(a, bfr1[kt], acc1, 0, 0, 0);
                }

                // ---- flow-gate (+ fused anti when D3) ----
                if (D3) {
                    if (tid < 32) {           // lanes 0..15: L0>=s; 16..31: L1>=s-1
                        unsigned thr = (tid < 16) ? (unsigned)s
                                                  : (unsigned)(s > 0 ? s - 1 : 0);
                        const unsigned* tp = gt + (size_t)tid * 32;
                        while (tagld(tp) < thr) __builtin_amdgcn_s_sleep(1);
                    }
                } else {
                    if (tid < 16) {
                        const unsigned* tp = gt + (size_t)tid * 32;
                        while (tagld(tp) < (unsigned)s) __builtin_amdgcn_s_sleep(1);
                    }
                }
                __syncthreads();              // (B)

                // ---- stage h0(s-1): 16 rows x 64 chunks (16 B) ----
#pragma unroll
                for (int i = 0; i < 4; ++i) {
                    int task = tid + i * 256;
                    int row = task >> 6, c8 = task & 63;
                    const ull* sp = (const ull*)(hsrc0 + (size_t)(rH * 128 + g * 16 + row) * 512 + c8 * 8);
                    ull v0 = __hip_atomic_load(sp,     __ATOMIC_RELAXED, __HIP_MEMORY_SCOPE_SYSTEM);
                    ull v1 = __hip_atomic_load(sp + 1, __ATOMIC_RELAXED, __HIP_MEMORY_SCOPE_SYSTEM);
                    ull* d = (ull*)(At + row * PITCH + 512 + c8 * 16);
                    d[0] = v0; d[1] = v1;
                }
                __syncthreads();              // (C) h staged

                // ---- h-half MFMAs (kt 8..23) ----
#pragma unroll
                for (int kt = KTX; kt < KT; ++kt) {
                    s16x8 a = *(const s16x8*)(ap + kt * 64);
                    acc0 = __builtin_amdgcn_mfma_f32_16x16x32_bf16(a, bfr0[kt], acc0, 0, 0, 0);
                    acc1 = __builtin_amdgcn_mfma_f32_16x16x32_bf16(a, bfr1[kt], acc1, 0, 0, 0);
                }
            } else {
                // ---- own-gate: 16 L1 tags >= s ----
                if (tid < 16) {
                    const unsigned* tp = gt + (size_t)(16 + tid) * 32;
                    while (tagld(tp) < (unsigned)s) __builtin_amdgcn_s_sleep(1);
                }
                __syncthreads();              // (B1)

                // ---- stage h1(s-1) -> At bytes 1024+ ----
#pragma unroll
                for (int i = 0; i < 4; ++i) {
                    int task = tid + i * 256;
                    int row = task >> 6, c8 = task & 63;
                    const ull* sp = (const ull*)(hself + (size_t)(pr2 * 128 + g * 16 + row) * 512 + c8 * 8);
                    ull v0 = __hip_atomic_load(sp,     __ATOMIC_RELAXED, __HIP_MEMORY_SCOPE_SYSTEM);
                    ull v1 = __hip_atomic_load(sp + 1, __ATOMIC_RELAXED, __HIP_MEMORY_SCOPE_SYSTEM);
                    ull* d = (ull*)(At + row * PITCH + 1024 + c8 * 16);
                    d[0] = v0; d[1] = v1;
                }
                __syncthreads();              // (C1) h1 staged

                // ---- h1-half MFMAs (kt 16..31) — overlap the wait for L0 ----
#pragma unroll
                for (int kt = KTY; kt < KT; ++kt) {
                    s16x8 a = *(const s16x8*)(ap + kt * 64);
                    acc0 = __builtin_amdgcn_mfma_f32_16x16x32_bf16(a, bfr0[kt], acc0, 0, 0, 0);
                    acc1 = __builtin_amdgcn_mfma_f32_16x16x32_bf16(a, bfr1[kt], acc1, 0, 0, 0);
                }

                // ---- cross-gate: 16 L0 tags >= s ----
                if (tid < 16) {
                    const unsigned* tp = gt + (size_t)tid * 32;
                    while (tagld(tp) < (unsigned)s) __builtin_amdgcn_s_sleep(1);
                }
                __syncthreads();              // (B2)

                // ---- stage y0(s-1) -> At bytes 0..1023 ----
#pragma unroll
                for (int i = 0; i < 4; ++i) {
                    int task = tid + i * 256;
                    int row = task >> 6, c8 = task & 63;
                    const ull* sp = (const ull*)(hsrc0 + (size_t)(rH * 128 + g * 16 + row) * 512 + c8 * 8);
                    ull v0 = __hip_atomic_load(sp,     __ATOMIC_RELAXED, __HIP_MEMORY_SCOPE_SYSTEM);
                    ull v1 = __hip_atomic_load(sp + 1, __ATOMIC_RELAXED, __HIP_MEMORY_SCOPE_SYSTEM);
                    ull* d = (ull*)(At + row * PITCH + c8 * 16);
                    d[0] = v0; d[1] = v1;
                }
                __syncthreads();              // (C2) y0 staged

                // ---- y0-half MFMAs (kt 0..15) ----
#pragma unroll
                for (int kt = 0; kt < KTY; ++kt) {
                    s16x8 a = *(const s16x8*)(ap + kt * 64);
                    acc0 = __builtin_amdgcn_mfma_f32_16x16x32_bf16(a, bfr0[kt], acc0, 0, 0, 0);
                    acc1 = __builtin_amdgcn_mfma_f32_16x16x32_bf16(a, bfr1[kt], acc1, 0, 0, 0);
                }
            }

            // ---- nonlinearity via shfl_xor(8,16); no LDS round trip ----
            const bool hi = (lm & 8) != 0;
            float hv[4];
#pragma unroll
            for (int r = 0; r < 4; ++r) {
                float a0 = acc0[r] + bv0;
                float a1 = acc1[r] + bv1;
                float a0x = __shfl_xor(a0, 8, 16);
                float a1x = __shfl_xor(a1, 8, 16);
                float iv = hi ? a0x : a0;
                float fv = hi ? a0  : a0x;
                float gv = hi ? a1x : a1;
                float ov = hi ? a1  : a1x;
                float cn = sigm(fv) * cst[r] + sigm(iv) * tanhc(gv);
                cst[r] = cn;
                hv[r] = sigm(ov) * tanhc(cn);
            }

            // ---- D2 fallback only: late anti-gate (L1 readers done) ----
            if (LAYER == 0 && !D3) {
                if (tid < 16) {
                    const unsigned* tp = gt + (size_t)(16 + tid) * 32;
                    while (tagld(tp) < (unsigned)s) __builtin_amdgcn_s_sleep(1);
                }
                __syncthreads();              // (E)
            }

            // ---- 8x4 register transpose -> packed 8-B h stores ----
            ull packed = 0;
#pragma unroll
            for (int r = 0; r < 4; ++r)
                packed |= ((ull)f2bf(hv[r])) << (16 * r);
            ull outp = 0;
            const int rp = (lm >> 1) & 3;
#pragma unroll
            for (int e = 0; e < 4; ++e) {
                ull got = __shfl(packed, (lm & 1) * 4 + e, 16);
                ull val = (got >> (16 * rp)) & 0xFFFFull;
                outp |= val << (16 * e);
            }
            if (lm < 8) {
                int brow = lq * 4 + (lm >> 1);
                int slot = (LAYER == 0) ? wH : pw2;
                size_t off = (size_t)(slot * 128 + g * 16 + brow) * 512
                           + rt * 32 + w * 8 + (lm & 1) * 4;
                __hip_atomic_store((ull*)(hself + off), outp,
                                   __ATOMIC_RELAXED, __HIP_MEMORY_SCOPE_SYSTEM);
            }
        }

        // ---- publish: syncthreads drains vmcnt(0) per wave, then tag ----
        __syncthreads();                      // (D)
        if (tid == 0)
            __hip_atomic_store(mytag, (unsigned)(s + 1),
                               __ATOMIC_RELAXED, __HIP_MEMORY_SCOPE_SYSTEM);

        if (D3) {
            sw3 = (sw3 == 2) ? 0 : sw3 + 1;
            sr3 = (sr3 == 2) ? 0 : sr3 + 1;
        }
    }
}

__launch_bounds__(256, 1)
__global__ void k_lstm(const float* __restrict__ x,
                       const float* __restrict__ b0,
                       const float* __restrict__ b1,
                       const unsigned short* __restrict__ wsB0,
                       const unsigned short* __restrict__ wsB1,
                       unsigned short* hb0, unsigned short* hb1,
                       unsigned* tags, int d3) {
    __shared__ __align__(16) char Atile[16 * 2112];      // A tile, max pitch (L1)

    const int tid = threadIdx.x;
    const int g = blockIdx.x & 7, sub = blockIdx.x >> 3;
    const int layer = sub >> 4, rt = sub & 15;
    const int w = tid >> 6, lane = tid & 63;
    const int lm = lane & 15;

    unsigned* gt = tags + (size_t)g * 32 * 32;           // 32 tags, 128-B spaced
    unsigned* mytag = gt + (size_t)(layer * 16 + rt) * 32;

    const float* bias = layer ? b1 : b0;
    const int jsub = rt * 32 + w * 8 + (lm & 7);
    const int G0 = (lm & 8) ? 1 : 0;                     // acc0: i | f
    const float bv0 = bias[G0 * 512 + jsub];
    const float bv1 = bias[(G0 + 2) * 512 + jsub];       // acc1: g | o

    if (layer == 0) {
        if (d3) run_layer<0, 24, true >(x, wsB0, hb0, hb0, gt, mytag, bv0, bv1,
                                        g, rt, w, lane, tid, Atile);
        else    run_layer<0, 24, false>(x, wsB0, hb0, hb0, gt, mytag, bv0, bv1,
                                        g, rt, w, lane, tid, Atile);
    } else {
        if (d3) run_layer<1, 32, true >(x, wsB1, hb0, hb1, gt, mytag, bv0, bv1,
                                        g, rt, w, lane, tid, Atile);
        else    run_layer<1, 32, false>(x, wsB1, hb0, hb1, gt, mytag, bv0, bv1,
                                        g, rt, w, lane, tid, Atile);
    }
}

// ---------------------------------------------------------------------------
// FC epilogue: out[i] = dot(hn[i], fc_w) + fc_b, hn = [h0(511); h1(511)]
// h0(511): epoch 511 -> slot 511%3 = 1 (D3) / 511&1 = 1 (D2) -> hb0+SLOT_W.
// h1(511): written at epoch 512 -> slot 0 (= hb1 base).
// ---------------------------------------------------------------------------
__global__ void k_fc(const unsigned short* __restrict__ hb0fin,
                     const unsigned short* __restrict__ hb1,
                     const float* __restrict__ fcw, const float* __restrict__ fcb,
                     float* __restrict__ out) {
    int i = blockIdx.x, lane = threadIdx.x;
    const unsigned short* hrow = (i < 128) ? (hb0fin + (size_t)i * 512)
                                           : (hb1 + (size_t)(i - 128) * 512);
    float ssum = 0.f;
    int j0 = lane * 8;
#pragma unroll
    for (int e = 0; e < 8; ++e) ssum += bf2f(hrow[j0 + e]) * fcw[j0 + e];
#pragma unroll
    for (int off2 = 32; off2 > 0; off2 >>= 1) ssum += __shfl_down(ssum, off2);
    if (lane == 0) out[i] = ssum + fcb[0];
}

// ---------------------------------------------------------------------------
extern "C" void kernel_launch(void* const* d_in, const int* in_sizes, int n_in,
                              void* d_out, int out_size, void* d_ws, size_t ws_size,
                              hipStream_t stream) {
    const float* x    = (const float*)d_in[0];
    const float* wih0 = (const float*)d_in[1];
    const float* whh0 = (const float*)d_in[2];
    const float* b0   = (const float*)d_in[3];
    const float* wih1 = (const float*)d_in[4];
    const float* whh1 = (const float*)d_in[5];
    const float* b1   = (const float*)d_in[6];
    const float* fcw  = (const float*)d_in[7];
    const float* fcb  = (const float*)d_in[8];

    // D3 layout: hb0 3 slots + hb1 2 slots end at byte 7995392; scattered
    // tags (256 x 128 B = 32 KB) at 7995392, end 8028160. D2 fallback:
    // round-10 layout exactly (tags at 7864320).
    const int d3 = (ws_size >= (size_t)8028160) ? 1 : 0;

    unsigned short* wsB0 = (unsigned short*)d_ws;
    unsigned short* wsB1 = wsB0 + WSB1_OFF;
    unsigned short* hb0  = wsB0 + HB0_OFF;
    unsigned short* hb1  = hb0 + (d3 ? 3 : 2) * SLOT_W;
    unsigned* tags = (unsigned*)((char*)d_ws + (d3 ? 7995392 : 7864320));
    unsigned short* hb0fin = hb0 + SLOT_W;               // slot 1 (both layouts)
    float* out = (float*)d_out;

    k_prep<<<dim3(1857), dim3(256), 0, stream>>>(wih0, whh0, wih1, whh1,
                                                 wsB0, wsB1, hb0, hb1, tags, d3);

    k_lstm<<<dim3(256), dim3(256), 0, stream>>>(x, b0, b1, wsB0, wsB1, hb0, hb1,
                                                tags, d3);

    k_fc<<<dim3(256), dim3(64), 0, stream>>>(hb0fin, hb1, fcw, fcb, out);
}